// Round 10
// baseline (488.279 us; speedup 1.0000x reference)
//
#include <hip/hip_runtime.h>
#include <hip/hip_fp16.h>
#include <math.h>

#define DD 256
#define NHEADS 8
#define HDIM 32
#define NLAYERS 2
#define GSZ 64
#define KGRID 4096      // GS*GS
#define TTASK 4
#define BB 4
#define NMEAS 511
#define SSRC 512        // N+1
#define HCITY 128
#define WCITY 128
#define ATT_SCALE 0.17677669529663687f   // 32^-0.5
#define INV2S2 78.125f                   // 1/(2*0.08^2)
#define LOG2E 1.4426950408889634f

typedef unsigned short u16;
typedef __attribute__((ext_vector_type(8))) short short8;
typedef __attribute__((ext_vector_type(4))) float f32x4;

__device__ __forceinline__ u16 f2bf(float f) {
    union { float f; unsigned int u; } x; x.f = f;
    return (u16)((x.u + 0x7fffu + ((x.u >> 16) & 1u)) >> 16);
}
__device__ __forceinline__ unsigned int cvtpk_bf16(float a, float b) {
    unsigned int r;
    asm("v_cvt_pk_bf16_f32 %0, %1, %2" : "=v"(r) : "v"(a), "v"(b));
    return r;
}
__device__ __forceinline__ float h2f(unsigned int u) {
    float r;
    asm("v_cvt_f32_f16 %0, %1" : "=v"(r) : "v"(u));
    return r;
}
__device__ __forceinline__ float gelu_f(float x) {
    return 0.5f * x * (1.0f + erff(x * 0.7071067811865476f));
}
__device__ __forceinline__ void gload16(const u16* g, u16* l) {
    __builtin_amdgcn_global_load_lds(
        (__attribute__((address_space(1))) void*)g,
        (__attribute__((address_space(3))) void*)l, 16, 0, 0);
}

// ---------------------------------------------------------------------------
// prep1: src_build (blocks 0..2047) + task_vec (blocks 2048..2051)
__global__ __launch_bounds__(256) void prep1_kernel(
    const float* __restrict__ meas_xy, const float* __restrict__ meas_v,
    const float* __restrict__ bs_xy, const float* __restrict__ city,
    const float* __restrict__ meas_W, const float* __restrict__ meas_b,
    const float* __restrict__ pW1, const float* __restrict__ pb1,
    const float* __restrict__ pW2, const float* __restrict__ pb2,
    const float* __restrict__ bs_W, const float* __restrict__ bs_b,
    const float* __restrict__ task_emb, const float* __restrict__ tpW,
    const float* __restrict__ tpb, const int* __restrict__ task_id,
    float* __restrict__ src, float* __restrict__ src_xy, float* __restrict__ tv) {
    __shared__ float sp[81];
    __shared__ float sh[DD];
    int blk = blockIdx.x, t = threadIdx.x;
    if (blk >= BB * SSRC) {               // task_vec
        int b = blk - BB * SSRC;
        int id = task_id[b];
        float a = tpb[t];
        for (int e = 0; e < DD; e++) a = fmaf(task_emb[id * DD + e], tpW[e * DD + t], a);
        tv[b * DD + t] = a;
        return;
    }
    int b = blk / SSRC, s = blk % SSRC;
    if (s < NMEAS) {
        float mx = meas_xy[(b * NMEAS + s) * 2];
        float my = meas_xy[(b * NMEAS + s) * 2 + 1];
        float mv = meas_v[b * NMEAS + s];
        int cx = (int)rintf(mx * 127.0f); cx = min(max(cx, 0), 127);
        int cy = (int)rintf(my * 127.0f); cy = min(max(cy, 0), 127);
        if (t < 81) {
            int rr = cy + t / 9 - 4, cc = cx + t % 9 - 4;
            sp[t] = (rr >= 0 && rr < HCITY && cc >= 0 && cc < WCITY)
                        ? city[(b * HCITY + rr) * WCITY + cc] : 0.0f;
        }
        __syncthreads();
        float a1 = pb1[t];
        #pragma unroll 9
        for (int e = 0; e < 81; e++) a1 = fmaf(sp[e], pW1[e * DD + t], a1);
        sh[t] = gelu_f(a1);
        __syncthreads();
        float a2 = pb2[t];
        for (int e = 0; e < DD; e++) a2 = fmaf(sh[e], pW2[e * DD + t], a2);
        float mt = mx * meas_W[t] + my * meas_W[DD + t] + mv * meas_W[2 * DD + t] + meas_b[t];
        src[((size_t)(b * SSRC + s)) * DD + t] = mt + a2;
        if (t == 0) { src_xy[(b * SSRC + s) * 2] = mx; src_xy[(b * SSRC + s) * 2 + 1] = my; }
    } else {
        float bx = bs_xy[b * 2], by = bs_xy[b * 2 + 1];
        src[((size_t)(b * SSRC + s)) * DD + t] = bx * bs_W[t] + by * bs_W[DD + t] + bs_b[t];
        if (t == 0) { src_xy[(b * SSRC + s) * 2] = bx; src_xy[(b * SSRC + s) * 2 + 1] = by; }
    }
}

// ---------------------------------------------------------------------------
// prep2: grid_init (0..4095) + density (4096..8191) + dist (8192..24575)
__global__ __launch_bounds__(256) void prep2_kernel(
    const float* __restrict__ grid_pos, const float* __restrict__ tv,
    const float* __restrict__ meas_xy, const float* __restrict__ sxy_g,
    float* __restrict__ g, float* __restrict__ dens, u16* __restrict__ dt) {
    __shared__ float2 sxy[SSRC];
    int id = blockIdx.x, t = threadIdx.x;
    if (id < 4096) {                      // grid_init
        int f = id * 256 + t;
        int b = f >> 18;
        float4 gp = ((const float4*)grid_pos)[f & 262143];
        float4 tvv = ((const float4*)tv)[b * 64 + (f & 63)];
        float4 o; o.x = gp.x + tvv.x; o.y = gp.y + tvv.y; o.z = gp.z + tvv.z; o.w = gp.w + tvv.w;
        ((float4*)g)[f] = o;
    } else if (id < 8192) {               // density
        int w = t >> 6, lane = t & 63;
        int idx = (id - 4096) * 4 + w;
        int b = idx >> 12, k = idx & 4095;
        float gx = ((k & 63) + 0.5f) * (1.0f / 64.0f);
        float gy = ((k >> 6) + 0.5f) * (1.0f / 64.0f);
        float s = 0.0f;
        for (int n = lane; n < NMEAS; n += 64) {
            float2 xy = ((const float2*)meas_xy)[b * NMEAS + n];
            float dx = gx - xy.x, dy = gy - xy.y;
            s += __expf(-(dx * dx + dy * dy) * INV2S2);
        }
        #pragma unroll
        for (int o = 1; o < 64; o <<= 1) s += __shfl_xor(s, o, 64);
        if (lane == 0) dens[idx] = s * (1.0f / 511.0f);
    } else {                              // dist table
        int bk = id - 8192;
        int b = bk >> 12, k = bk & 4095;
        sxy[t]       = ((const float2*)sxy_g)[b * SSRC + t];
        sxy[t + 256] = ((const float2*)sxy_g)[b * SSRC + t + 256];
        __syncthreads();
        float gx = ((k & 63) + 0.5f) * (1.0f / 64.0f);
        float gy = ((k >> 6) + 0.5f) * (1.0f / 64.0f);
        float2 p0 = sxy[2 * t], p1 = sxy[2 * t + 1];
        float dx0 = gx - p0.x, dy0 = gy - p0.y;
        float dx1 = gx - p1.x, dy1 = gy - p1.y;
        float d0 = sqrtf(dx0 * dx0 + dy0 * dy0);
        float d1 = sqrtf(dx1 * dx1 + dy1 * dy1);
        __half h0 = __float2half(d0), h1 = __float2half(d1);
        unsigned int pk = (unsigned int)__half_as_ushort(h0) |
                          ((unsigned int)__half_as_ushort(h1) << 16);
        ((unsigned int*)dt)[(size_t)bk * 256 + t] = pk;
    }
}

// ---------------------------------------------------------------------------
// wconv body: one 32x32 tile of W[z][Kd][Nd] fp32 -> Wt[z*ostride+(noff+n)*Kd+k] bf16
__device__ __forceinline__ void wconv_body(const float* W, u16* Wt, int Kd, int Nd,
                                           int ostride, int noff, int z, int n0, int k0,
                                           int t, float* L) {
    int tx = t & 31, ty = t >> 5;
    size_t zin = (size_t)z * Kd * Nd;
    #pragma unroll
    for (int yy = 0; yy < 4; yy++)
        L[tx * 33 + ty + 8 * yy] = W[zin + (size_t)(k0 + ty + 8 * yy) * Nd + n0 + tx];
    __syncthreads();
    #pragma unroll
    for (int yy = 0; yy < 4; yy++)
        Wt[(size_t)z * ostride + (size_t)(noff + n0 + ty + 8 * yy) * Kd + k0 + tx] =
            f2bf(L[(ty + 8 * yy) * 33 + tx]);
}

// prep3: all weight converts + params (gate tables, kv bias, d_out init)
__global__ __launch_bounds__(256) void prep3_kernel(
    const float* __restrict__ qW, const float* __restrict__ kW,
    const float* __restrict__ vW, const float* __restrict__ oW,
    const float* __restrict__ f1W, const float* __restrict__ f2W,
    const float* __restrict__ tfp_W,
    u16* __restrict__ wtq, u16* __restrict__ wkv, u16* __restrict__ wto,
    u16* __restrict__ wtf1, u16* __restrict__ wtf2, u16* __restrict__ wtt,
    const float* __restrict__ dens, const float* __restrict__ dist_raw,
    const float* __restrict__ dens_raw, const float* __restrict__ kb,
    const float* __restrict__ vb, const float* __restrict__ hb,
    float* __restrict__ gsc, float* __restrict__ gcc,
    float* __restrict__ kvb, float* __restrict__ out) {
    __shared__ float L[32 * 33];
    int id = blockIdx.x, t = threadIdx.x;
    if (id < 512) {          // q,k,v,o: 128 blocks each (z=id>>6 within segment of 128)
        int seg = id >> 7, lid = id & 127;
        int z = lid >> 6, rem = lid & 63;
        int n0 = (rem & 7) * 32, k0 = (rem >> 3) * 32;
        if (seg == 0)      wconv_body(qW, wtq, 256, 256, 65536, 0, z, n0, k0, t, L);
        else if (seg == 1) wconv_body(kW, wkv, 256, 256, 131072, 0, z, n0, k0, t, L);
        else if (seg == 2) wconv_body(vW, wkv, 256, 256, 131072, 256, z, n0, k0, t, L);
        else               wconv_body(oW, wto, 256, 256, 65536, 0, z, n0, k0, t, L);
    } else if (id < 768) {   // f1: Nd=512: 16 n-tiles x 8 k-tiles x 2
        int lid = id - 512;
        int z = lid >> 7, rem = lid & 127;
        int n0 = (rem & 15) * 32, k0 = (rem >> 4) * 32;
        wconv_body(f1W, wtf1, 256, 512, 131072, 0, z, n0, k0, t, L);
    } else if (id < 1024) {  // f2: Kd=512: 8 n-tiles x 16 k-tiles x 2
        int lid = id - 768;
        int z = lid >> 7, rem = lid & 127;
        int n0 = (rem & 7) * 32, k0 = (rem >> 3) * 32;
        wconv_body(f2W, wtf2, 512, 256, 131072, 0, z, n0, k0, t, L);
    } else if (id < 1280) {  // tfp: 4 z
        int lid = id - 1024;
        int z = lid >> 6, rem = lid & 63;
        int n0 = (rem & 7) * 32, k0 = (rem >> 3) * 32;
        wconv_body(tfp_W, wtt, 256, 256, 65536, 0, z, n0, k0, t, L);
    } else {                 // params
        int idx = (id - 1280) * 256 + t;   // 0..32767
        int l = idx >> 14, i = idx & 16383;
        float gate = 1.0f + tanhf(dens_raw[l]) * dens[i];
        gsc[idx] = gate * ATT_SCALE * LOG2E;
        gcc[idx] = gate * log1pf(__expf(dist_raw[l])) * LOG2E;
        if (idx < 16384) out[idx] = hb[0];
        if (idx < 1024) {
            int ll = idx >> 9, c = idx & 511;
            kvb[idx] = (c < 256) ? kb[ll * 256 + c] : vb[ll * 256 + c - 256];
        }
    }
}

// ---------------------------------------------------------------------------
// LN body (one wave per row of 256, bf16 out)
__device__ __forceinline__ void ln_body(const float* X, const float* g,
                                        const float* bvec, u16* Yb, int row, int lane) {
    float4 x = ((const float4*)X)[(size_t)row * 64 + lane];
    float s = x.x + x.y + x.z + x.w;
    float q = x.x * x.x + x.y * x.y + x.z * x.z + x.w * x.w;
    #pragma unroll
    for (int o = 1; o < 64; o <<= 1) { s += __shfl_xor(s, o, 64); q += __shfl_xor(q, o, 64); }
    float m = s * (1.0f / 256.0f);
    float v = q * (1.0f / 256.0f) - m * m;
    float rs = rsqrtf(v + 1e-5f);
    float4 gg = ((const float4*)g)[lane], bb = ((const float4*)bvec)[lane];
    float4 y;
    y.x = (x.x - m) * rs * gg.x + bb.x;
    y.y = (x.y - m) * rs * gg.y + bb.y;
    y.z = (x.z - m) * rs * gg.z + bb.z;
    y.w = (x.w - m) * rs * gg.w + bb.w;
    uint2 o2;
    o2.x = cvtpk_bf16(y.x, y.y);
    o2.y = cvtpk_bf16(y.z, y.w);
    *(uint2*)&Yb[(size_t)row * 256 + lane * 4] = o2;
}

__global__ void ln_kernel(const float* __restrict__ X, const float* __restrict__ g,
                          const float* __restrict__ bvec, u16* __restrict__ Yb, int rows) {
    int w = threadIdx.x >> 6, lane = threadIdx.x & 63;
    int row = blockIdx.x * 4 + w;
    if (row < rows) ln_body(X, g, bvec, Yb, row, lane);
}

// ln2: kv-LN (blocks 0..511) + q-LN (512..4607)
__global__ void ln2_kernel(const float* __restrict__ Xkv, const float* __restrict__ gkv,
                           const float* __restrict__ bkv, u16* __restrict__ Ykv,
                           const float* __restrict__ Xq, const float* __restrict__ gq,
                           const float* __restrict__ bq, u16* __restrict__ Yq) {
    int w = threadIdx.x >> 6, lane = threadIdx.x & 63;
    int blk = blockIdx.x;
    if (blk < 512) ln_body(Xkv, gkv, bkv, Ykv, blk * 4 + w, lane);
    else           ln_body(Xq, gq, bq, Yq, (blk - 512) * 4 + w, lane);
}

// ---------------------------------------------------------------------------
// V transpose: V[(b*512+s)*512 + 256 + n] bf16 -> Vt[(b*256+n)][512] bf16.
__global__ __launch_bounds__(256) void vtrans_kernel(const u16* __restrict__ V,
                                                     u16* __restrict__ Vt,
                                                     int instride, int inoff) {
    __shared__ u16 L[32][33];
    int b = blockIdx.z;
    int n0 = blockIdx.x * 32, s0 = blockIdx.y * 32;
    int tx = threadIdx.x, ty = threadIdx.y;
    #pragma unroll
    for (int yy = 0; yy < 4; yy++)
        L[tx][ty + 8 * yy] = V[(size_t)(b * SSRC + s0 + ty + 8 * yy) * instride + inoff + n0 + tx];
    __syncthreads();
    #pragma unroll
    for (int yy = 0; yy < 4; yy++)
        Vt[(size_t)(b * DD + n0 + ty + 8 * yy) * SSRC + s0 + tx] = L[ty + 8 * yy][tx];
}

// ---------------------------------------------------------------------------
// m97-style bf16 MFMA GEMM core. Tile 128x128, BK=32, 4 waves (64x64, 4x4 frags),
// global_load_lds staging, double-buffered.
template <int ACT, int RES, int OBF, int OF32, int RS, int HEAD, int KD>
__device__ __forceinline__ void gemm_core(
    const u16* A, const u16* Wp, const float* bp, float* C, u16* Cb,
    int Nfull, int m0, int n0, const float* rs, const float* hw,
    u16 (*sA)[128][32], u16 (*sB)[128][32]) {
    int t = threadIdx.x;
    int w = t >> 6, lane = t & 63, lq = lane & 15, g = lane >> 4;
    int wr = w >> 1, wc = w & 1;
    int srow = lane >> 2;
    int scol = (lane & 3) * 8;
    const u16* Ag0 = A  + (size_t)(m0 + w * 32 + srow) * KD + scol;
    const u16* Ag1 = Ag0 + (size_t)16 * KD;
    const u16* Bg0 = Wp + (size_t)(n0 + w * 32 + srow) * KD + scol;
    const u16* Bg1 = Bg0 + (size_t)16 * KD;

    f32x4 acc[4][4];
    #pragma unroll
    for (int fm = 0; fm < 4; fm++)
        #pragma unroll
        for (int fn = 0; fn < 4; fn++) acc[fm][fn] = {0.f, 0.f, 0.f, 0.f};

    const int NKS = KD / 32;
    gload16(Ag0, &sA[0][w * 32][0]);
    gload16(Ag1, &sA[0][w * 32 + 16][0]);
    gload16(Bg0, &sB[0][w * 32][0]);
    gload16(Bg1, &sB[0][w * 32 + 16][0]);
    __syncthreads();

    #pragma unroll
    for (int ks = 0; ks < NKS; ks++) {
        int cur = ks & 1;
        if (ks + 1 < NKS) {
            int ko = (ks + 1) * 32;
            gload16(Ag0 + ko, &sA[cur ^ 1][w * 32][0]);
            gload16(Ag1 + ko, &sA[cur ^ 1][w * 32 + 16][0]);
            gload16(Bg0 + ko, &sB[cur ^ 1][w * 32][0]);
            gload16(Bg1 + ko, &sB[cur ^ 1][w * 32 + 16][0]);
        }
        short8 af[4], bf[4];
        #pragma unroll
        for (int fm = 0; fm < 4; fm++)
            af[fm] = *(const short8*)&sA[cur][wr * 64 + fm * 16 + lq][g * 8];
        #pragma unroll
        for (int fn = 0; fn < 4; fn++)
            bf[fn] = *(const short8*)&sB[cur][wc * 64 + fn * 16 + lq][g * 8];
        #pragma unroll
        for (int fm = 0; fm < 4; fm++)
            #pragma unroll
            for (int fn = 0; fn < 4; fn++)
                acc[fm][fn] = __builtin_amdgcn_mfma_f32_16x16x32_bf16(af[fm], bf[fn], acc[fm][fn], 0, 0, 0);
        __syncthreads();
    }

    float hWv[4], bv[4];
    #pragma unroll
    for (int fn = 0; fn < 4; fn++) {
        int col = n0 + wc * 64 + fn * 16 + lq;
        bv[fn] = bp[col];
        if (HEAD) hWv[fn] = hw[col];
    }
    #pragma unroll
    for (int fm = 0; fm < 4; fm++) {
        int mbase = m0 + wr * 64 + fm * 16 + 4 * g;
        if (HEAD) {
            #pragma unroll
            for (int r = 0; r < 4; r++) {
                float part = 0.0f;
                #pragma unroll
                for (int fn = 0; fn < 4; fn++) {
                    float o = acc[fm][fn][r] + bv[fn];
                    if (ACT) o = gelu_f(o);
                    part = fmaf(o, hWv[fn], part);
                }
                part += __shfl_xor(part, 1, 64);
                part += __shfl_xor(part, 2, 64);
                part += __shfl_xor(part, 4, 64);
                part += __shfl_xor(part, 8, 64);
                if (lq == 0) atomicAdd(&C[mbase + r], part);
            }
        } else {
            #pragma unroll
            for (int fn = 0; fn < 4; fn++) {
                int col = n0 + wc * 64 + fn * 16 + lq;
                #pragma unroll
                for (int r = 0; r < 4; r++) {
                    float o = acc[fm][fn][r] + bv[fn];
                    if (RS) o *= rs[mbase + r];
                    if (ACT) o = gelu_f(o);
                    size_t off = (size_t)(mbase + r) * Nfull + col;
                    if (RES) o += C[off];
                    if (OF32) C[off] = o;
                    if (OBF) Cb[off] = f2bf(o);
                }
            }
        }
    }
}

template <int ACT, int RES, int OBF, int OF32, int BATW, int RS, int HEAD, int KD>
__global__ __launch_bounds__(256) void gemm_glds(
    const u16* __restrict__ A, const u16* __restrict__ Wt,
    const float* __restrict__ bias, float* __restrict__ C, u16* __restrict__ Cb,
    int Nfull, const int* __restrict__ task_id, int wstride, int bstride,
    const float* __restrict__ rs, const float* __restrict__ hw) {
    __shared__ u16 sA[2][128][32];
    __shared__ u16 sB[2][128][32];
    int m0 = blockIdx.x * 128, n0 = blockIdx.y * 128;
    const u16* Wp = Wt;
    const float* bp = bias;
    if (BATW) {
        int id = task_id[m0 / KGRID];
        Wp += (size_t)id * wstride;
        bp += (size_t)id * bstride;
    }
    gemm_core<ACT, RES, OBF, OF32, RS, HEAD, KD>(A, Wp, bp, C, Cb, Nfull, m0, n0, rs, hw, sA, sB);
}

// kv-gemm (y==2, 64 blocks) + q-gemm (y<2, 256 blocks) in one dispatch.
__global__ __launch_bounds__(256) void gemm_kvq_kernel(
    const u16* __restrict__ kvbf, const u16* __restrict__ wkv,
    const float* __restrict__ kvb, u16* __restrict__ kvo,
    const u16* __restrict__ lnbf, const u16* __restrict__ wtq,
    const float* __restrict__ qb, u16* __restrict__ qbf,
    const float* __restrict__ gsc) {
    __shared__ u16 sA[2][128][32];
    __shared__ u16 sB[2][128][32];
    if (blockIdx.y == 2) {
        if (blockIdx.x >= 64) return;
        int m0 = (blockIdx.x & 15) * 128, n0 = (blockIdx.x >> 4) * 128;
        gemm_core<0, 0, 1, 0, 0, 0, 256>(kvbf, wkv, kvb, nullptr, kvo, 512, m0, n0,
                                         nullptr, nullptr, sA, sB);
    } else {
        int m0 = blockIdx.x * 128, n0 = blockIdx.y * 128;
        gemm_core<0, 0, 1, 0, 1, 0, 256>(lnbf, wtq, qb, nullptr, qbf, 256, m0, n0,
                                         gsc, nullptr, sA, sB);
    }
}

// ---------------------------------------------------------------------------
// MFMA attention v5 (unchanged from R9): Q pre-scaled; gc table; dist slab LDS;
// sP rows padded to 40 u16. Block = (b, 32 q) x 8 waves = 8 heads.
#define DPAD 520
#define PSTR 40
__global__ __launch_bounds__(512) void attn_mfma_kernel(
    const u16* __restrict__ Qb, const u16* __restrict__ KVo, const u16* __restrict__ Vt,
    const u16* __restrict__ distT, const float* __restrict__ gccL,
    u16* __restrict__ O) {
    __shared__ u16 sD[32][DPAD];
    __shared__ u16 sP[16][16 * PSTR];
    int blk = blockIdx.x;                // b*128 + kt
    int kt = blk & 127, b = blk >> 7;
    int t = threadIdx.x;
    {
        int r = t >> 4, cs = (t & 15) * 32;
        const u16* gp = distT + ((size_t)(b * KGRID) + kt * 32 + r) * SSRC + cs;
        uint4 d0 = *(const uint4*)gp;
        uint4 d1 = *(const uint4*)(gp + 8);
        uint4 d2 = *(const uint4*)(gp + 16);
        uint4 d3 = *(const uint4*)(gp + 24);
        *(uint4*)&sD[r][cs] = d0;
        *(uint4*)&sD[r][cs + 8] = d1;
        *(uint4*)&sD[r][cs + 16] = d2;
        *(uint4*)&sD[r][cs + 24] = d3;
    }
    __syncthreads();

    int w = t >> 6, lane = t & 63, lq = lane & 15, g = lane >> 4;
    int h = w;
    float gc[2];
    short8 qf[2];
    #pragma unroll
    for (int qc = 0; qc < 2; qc++) {
        int qrow = kt * 32 + qc * 16 + lq;
        gc[qc] = gccL[b * KGRID + qrow];
        qf[qc] = *(const short8*)(Qb + (size_t)(b * KGRID + qrow) * DD + h * HDIM + g * 8);
    }
    const u16* kbase = KVo + (size_t)(b * SSRC) * 512 + h * HDIM + g * 8;
    const u16* vbase = Vt + ((size_t)(b * NHEADS + h) * HDIM + lq) * SSRC + g * 8;

    f32x4 accA[2] = {{0.f, 0.f, 0.f, 0.f}, {0.f, 0.f, 0.f, 0.f}};
    f32x4 accB[2] = {{0.f, 0.f, 0.f, 0.f}, {0.f, 0.f, 0.f, 0.f}};
    f32x4 zero = {0.f, 0.f, 0.f, 0.f};
    float lsum[2] = {0.f, 0.f};

    for (int s0 = 0; s0 < SSRC; s0 += 32) {
        #pragma unroll
        for (int tl = 0; tl < 2; tl++) {
            int sb = s0 + tl * 16;
            short8 kf = *(const short8*)(kbase + (size_t)(sb + lq) * 512);
            #pragma unroll
            for (int qc = 0; qc < 2; qc++) {
                f32x4 c = __builtin_amdgcn_mfma_f32_16x16x32_bf16(kf, qf[qc], zero, 0, 0, 0);
                uint2 dh = *(const uint2*)&sD[qc * 16 + lq][sb + 4 * g];
                float p0 = exp2f(fmaf(-gc[qc], h2f(dh.x), c[0]));
                float p1 = exp2f(fmaf(-gc[qc], h2f(dh.x >> 16), c[1]));
                float p2 = exp2f(fmaf(-gc[qc], h2f(dh.y), c[2]));
                float p3 = exp2f(fmaf(-gc[qc], h2f(dh.y >> 16), c[3]));
                lsum[qc] += (p0 + p1) + (p2 + p3);
                int idx = lq * PSTR + tl * 16 + 4 * g;
                *(unsigned int*)&sP[w * 2 + qc][idx]     = cvtpk_bf16(p0, p1);
                *(unsigned int*)&sP[w * 2 + qc][idx + 2] = cvtpk_bf16(p2, p3);
            }
        }
        short8 v0 = *(const short8*)(vbase + s0);
        short8 v1 = *(const short8*)(vbase + 16 * SSRC + s0);
        #pragma unroll
        for (int qc = 0; qc < 2; qc++) {
            short8 pf = *(const short8*)&sP[w * 2 + qc][lq * PSTR + g * 8];
            accA[qc] = __builtin_amdgcn_mfma_f32_16x16x32_bf16(v0, pf, accA[qc], 0, 0, 0);
            accB[qc] = __builtin_amdgcn_mfma_f32_16x16x32_bf16(v1, pf, accB[qc], 0, 0, 0);
        }
    }

    #pragma unroll
    for (int qc = 0; qc < 2; qc++) {
        float ls = lsum[qc];
        ls += __shfl_xor(ls, 16, 64);
        ls += __shfl_xor(ls, 32, 64);
        float inv = 1.0f / ls;
        int qrow = kt * 32 + qc * 16 + lq;
        u16* op = O + (size_t)(b * KGRID + qrow) * DD + h * HDIM + 4 * g;
        uint2 o0, o1;
        o0.x = cvtpk_bf16(accA[qc][0] * inv, accA[qc][1] * inv);
        o0.y = cvtpk_bf16(accA[qc][2] * inv, accA[qc][3] * inv);
        o1.x = cvtpk_bf16(accB[qc][0] * inv, accB[qc][1] * inv);
        o1.y = cvtpk_bf16(accB[qc][2] * inv, accB[qc][3] * inv);
        *(uint2*)op = o0;
        *(uint2*)(op + 16) = o1;
    }
}

// ---------------------------------------------------------------------------
extern "C" void kernel_launch(void* const* d_in, const int* in_sizes, int n_in,
                              void* d_out, int out_size, void* d_ws, size_t ws_size,
                              hipStream_t stream) {
    const float* meas_xy = (const float*)d_in[0];
    const float* meas_v  = (const float*)d_in[1];
    const float* bs_xy   = (const float*)d_in[2];
    const float* city    = (const float*)d_in[3];
    const float* meas_W  = (const float*)d_in[4];
    const float* meas_b  = (const float*)d_in[5];
    const float* pW1     = (const float*)d_in[6];
    const float* pb1     = (const float*)d_in[7];
    const float* pW2     = (const float*)d_in[8];
    const float* pb2     = (const float*)d_in[9];
    const float* bs_W    = (const float*)d_in[10];
    const float* bs_b    = (const float*)d_in[11];
    const float* task_emb= (const float*)d_in[12];
    const float* taskp_W = (const float*)d_in[13];
    const float* taskp_b = (const float*)d_in[14];
    const float* grid_pos= (const float*)d_in[15];
    const float* lnq_g   = (const float*)d_in[16];
    const float* lnq_b   = (const float*)d_in[17];
    const float* lnkv_g  = (const float*)d_in[18];
    const float* lnkv_b  = (const float*)d_in[19];
    const float* qW      = (const float*)d_in[20];
    const float* qb      = (const float*)d_in[21];
    const float* kW      = (const float*)d_in[22];
    const float* kb      = (const float*)d_in[23];
    const float* vW      = (const float*)d_in[24];
    const float* vb      = (const float*)d_in[25];
    const float* oW      = (const float*)d_in[26];
    const float* ob      = (const float*)d_in[27];
    const float* dist_raw= (const float*)d_in[28];
    const float* dens_raw= (const float*)d_in[29];
    const float* lnf_g   = (const float*)d_in[30];
    const float* lnf_b   = (const float*)d_in[31];
    const float* f1W     = (const float*)d_in[32];
    const float* f1b     = (const float*)d_in[33];
    const float* f2W     = (const float*)d_in[34];
    const float* f2b     = (const float*)d_in[35];
    const float* tfp_W   = (const float*)d_in[36];
    const float* tfp_b   = (const float*)d_in[37];
    const float* head_W  = (const float*)d_in[38];
    const float* head_b  = (const float*)d_in[39];
    const int*   task_id = (const int*)d_in[40];

    float* ws = (float*)d_ws;
    float* src   = ws;                       // 524288
    float* gridb = src + 524288;             // 4194304
    float* distTf= gridb + 4194304;          // 4194304
    float* sxyb  = distTf + 4194304;         // 4096
    float* densb = sxyb + 4096;              // 16384
    float* tvec  = densb + 16384;            // 1024
    float* gsc   = tvec + 1024;              // 32768
    float* gcc   = gsc + 32768;              // 32768
    float* kvb   = gcc + 32768;              // 1024

    u16* distT = (u16*)distTf;

    u16* wtq  = (u16*)(kvb + 1024);          // 131072
    u16* wto  = wtq  + 131072;               // 131072
    u16* wkv  = wto  + 131072;               // 262144
    u16* wtf1 = wkv  + 262144;               // 262144
    u16* wtf2 = wtf1 + 262144;               // 262144
    u16* wtt  = wtf2 + 262144;               // 262144
    u16* kvbf = wtt  + 262144;               // 524288
    u16* lnbf = kvbf + 524288;               // 4194304
    u16* qbf  = lnbf + 4194304;              // 4194304
    u16* kvo  = qbf  + 4194304;              // 1048576
    u16* vtbf = kvo  + 1048576;              // 524288
    u16* obf  = vtbf + 524288;               // 4194304
    u16* fhbf = obf  + 4194304;              // 8388608

    prep1_kernel<<<BB * SSRC + BB, 256, 0, stream>>>(
        meas_xy, meas_v, bs_xy, city, meas_W, meas_b, pW1, pb1, pW2, pb2,
        bs_W, bs_b, task_emb, taskp_W, taskp_b, task_id, src, sxyb, tvec);
    prep2_kernel<<<24576, 256, 0, stream>>>(grid_pos, tvec, meas_xy, sxyb,
                                            gridb, densb, distT);
    prep3_kernel<<<1408, 256, 0, stream>>>(
        qW, kW, vW, oW, f1W, f2W, tfp_W, wtq, wkv, wto, wtf1, wtf2, wtt,
        densb, dist_raw, dens_raw, kb, vb, head_b, gsc, gcc, kvb, (float*)d_out);

    for (int i = 0; i < NLAYERS; i++) {
        const int w16 = i * 65536, bso = i * DD;
        ln2_kernel<<<4608, 256, 0, stream>>>(src, lnkv_g + bso, lnkv_b + bso, kvbf,
                                             gridb, lnq_g + bso, lnq_b + bso, lnbf);
        gemm_kvq_kernel<<<dim3(128, 3), 256, 0, stream>>>(
            kvbf, wkv + i * 131072, kvb + i * 512, kvo,
            lnbf, wtq + w16, qb + bso, qbf, gsc + i * 16384);
        vtrans_kernel<<<dim3(8, 16, 4), dim3(32, 8), 0, stream>>>(kvo, vtbf, 512, 256);
        attn_mfma_kernel<<<BB * (KGRID / 32), 512, 0, stream>>>(
            qbf, kvo, vtbf, distT, gcc + i * 16384, obf);
        gemm_glds<0, 1, 0, 1, 0, 0, 0, 256><<<dim3(128, 2), 256, 0, stream>>>(
            obf, wto + w16, ob + bso, gridb, obf, 256, nullptr, 0, 0, nullptr, nullptr);
        ln_kernel<<<4096, 256, 0, stream>>>(gridb, lnf_g + bso, lnf_b + bso, lnbf, 16384);
        gemm_glds<1, 0, 1, 0, 0, 0, 0, 256><<<dim3(128, 4), 256, 0, stream>>>(
            lnbf, wtf1 + i * 131072, f1b + i * 512, nullptr, fhbf, 512, nullptr, 0, 0, nullptr, nullptr);
        gemm_glds<0, 1, 1, 1, 0, 0, 0, 512><<<dim3(128, 2), 256, 0, stream>>>(
            fhbf, wtf2 + i * 131072, f2b + bso, gridb, lnbf, 256, nullptr, 0, 0, nullptr, nullptr);
    }

    gemm_glds<1, 0, 0, 0, 1, 0, 1, 256><<<dim3(128, 2), 256, 0, stream>>>(
        lnbf, wtt, tfp_b, (float*)d_out, nullptr, 256, task_id, 65536, 256, nullptr, head_W);
}